// Round 2
// baseline (3210.085 us; speedup 1.0000x reference)
//
#include <hip/hip_runtime.h>
#include <hip/hip_bf16.h>

#define D 128

// ---------------- small utility kernels ----------------

__global__ void k_zero_i32(int* __restrict__ p, int n) {
    int i = blockIdx.x * blockDim.x + threadIdx.x;
    if (i < n) p[i] = 0;
}

__global__ void k_count_deg(const int* __restrict__ dst, int* __restrict__ deg, int e) {
    int i = blockIdx.x * blockDim.x + threadIdx.x;
    if (i < e) atomicAdd(&deg[dst[i]], 1);
}

__global__ void k_dis(const int* __restrict__ deg, float* __restrict__ dis, int n) {
    int i = blockIdx.x * blockDim.x + threadIdx.x;
    if (i < n) dis[i] = rsqrtf((float)deg[i] + 1.0f);
}

// ---------------- GEMM: C[n,128] = A[n,128] @ W[128,128] (+bias)(+relu) ----------------

__global__ __launch_bounds__(256) void k_gemm128(
    const float* __restrict__ A, const float* __restrict__ W,
    const float* __restrict__ bias, float* __restrict__ C, int n,
    int fuse_bias, int fuse_relu) {
    __shared__ float Ws[D * D];     // 64 KiB (ok on gfx950: 160 KiB/CU)
    __shared__ float As[8][D];      // 4 KiB
    int t = threadIdx.x;
    for (int i = t; i < D * D; i += 256) Ws[i] = W[i];
    int row0 = blockIdx.x * 8;
    for (int i = t; i < 8 * D; i += 256) {
        int r = i >> 7, c = i & 127;
        int gr = row0 + r;
        As[r][c] = (gr < n) ? A[(size_t)gr * D + c] : 0.0f;
    }
    __syncthreads();
    int col = t & 127;
    int rb = (t >> 7) * 4;           // rows rb..rb+3 of the 8-row tile
    float acc0 = 0.f, acc1 = 0.f, acc2 = 0.f, acc3 = 0.f;
    #pragma unroll 8
    for (int k = 0; k < D; ++k) {
        float w = Ws[k * D + col];
        acc0 = fmaf(As[rb + 0][k], w, acc0);
        acc1 = fmaf(As[rb + 1][k], w, acc1);
        acc2 = fmaf(As[rb + 2][k], w, acc2);
        acc3 = fmaf(As[rb + 3][k], w, acc3);
    }
    float bv = fuse_bias ? bias[col] : 0.0f;
    float accs[4] = {acc0, acc1, acc2, acc3};
    #pragma unroll
    for (int j = 0; j < 4; ++j) {
        int r = row0 + rb + j;
        if (r < n) {
            float v = accs[j] + bv;
            if (fuse_relu) v = fmaxf(v, 0.0f);
            C[(size_t)r * D + col] = v;
        }
    }
}

// ---------------- GCN aggregation ----------------

// AGG[v] = H[v] * dis[v]^2   (self-loop term; also zero-inits AGG)
__global__ void k_self_init(const float* __restrict__ H, const float* __restrict__ dis,
                            float* __restrict__ AGG, int n) {
    int i = blockIdx.x * blockDim.x + threadIdx.x;
    if (i < n * D) {
        int v = i >> 7;
        float d = dis[v];
        AGG[i] = H[i] * d * d;
    }
}

// AGG[dst] += dis[src]*dis[dst] * H[src]   (one thread per (edge, channel))
__global__ void k_edge_agg(const int* __restrict__ src, const int* __restrict__ dst,
                           const float* __restrict__ H, const float* __restrict__ dis,
                           float* __restrict__ AGG, int e) {
    long long idx = (long long)blockIdx.x * blockDim.x + threadIdx.x;
    int eid = (int)(idx >> 7);
    if (eid < e) {
        int c = (int)(idx & 127);
        int s = src[eid], d = dst[eid];
        float nrm = dis[s] * dis[d];
        atomicAdd(&AGG[(size_t)d * D + c], H[(size_t)s * D + c] * nrm);
    }
}

// X[v] = relu(AGG[v] + b)
__global__ void k_finalize_relu(const float* __restrict__ AGG, const float* __restrict__ bias,
                                float* __restrict__ X, int n) {
    int i = blockIdx.x * blockDim.x + threadIdx.x;
    if (i < n * D) {
        int c = i & 127;
        X[i] = fmaxf(AGG[i] + bias[c], 0.0f);
    }
}

// ---------------- launcher ----------------

extern "C" void kernel_launch(void* const* d_in, const int* in_sizes, int n_in,
                              void* d_out, int out_size, void* d_ws, size_t ws_size,
                              hipStream_t stream) {
    const float* x    = (const float*)d_in[0];
    const int*   ei   = (const int*)d_in[1];
    const float* xa   = (const float*)d_in[2];
    const int*   eia  = (const int*)d_in[3];
    const float* W_in = (const float*)d_in[4];
    const float* b_in = (const float*)d_in[5];
    const float* W_h  = (const float*)d_in[6];
    const float* b_h  = (const float*)d_in[7];
    const float* W_out= (const float*)d_in[8];
    const float* b_out= (const float*)d_in[9];
    const float* Wf1  = (const float*)d_in[10];
    const float* bf1  = (const float*)d_in[11];
    const float* Wf2  = (const float*)d_in[12];
    const float* bf2  = (const float*)d_in[13];

    const int n = in_sizes[0] / D;       // 50000
    const int e = in_sizes[1] / 2;       // 800000

    float* Xf  = (float*)d_ws;                   // activations [n,128]
    float* H   = Xf  + (size_t)n * D;            // X@W          [n,128]
    float* AGG = H   + (size_t)n * D;            // aggregation  [n,128]
    float* dis = AGG + (size_t)n * D;            // [n]
    int*   deg = (int*)(dis + n);                // [n]

    float* out = (float*)d_out;

    const float* Wl[3] = {W_in, W_h, W_out};
    const float* bl[3] = {b_in, b_h, b_out};

    const int threads = 256;
    const int g_nd   = (n * D + threads - 1) / threads;
    const int g_n    = (n + threads - 1) / threads;
    const int g_e    = (e + threads - 1) / threads;
    const long long edge_work = (long long)e * D;
    const int g_ed   = (int)((edge_work + threads - 1) / threads);
    const int g_gemm = (n + 7) / 8;

    for (int g = 0; g < 2; ++g) {
        const float* xin = g ? xa : x;
        const int* src  = g ? eia : ei;        // edge_index[0]
        const int* dst  = src + e;             // edge_index[1]
        float* outg = out + (size_t)g * n * D;

        k_zero_i32<<<g_n, threads, 0, stream>>>(deg, n);
        k_count_deg<<<g_e, threads, 0, stream>>>(dst, deg, e);
        k_dis<<<g_n, threads, 0, stream>>>(deg, dis, n);

        for (int l = 0; l < 3; ++l) {
            const float* Ain = (l == 0) ? xin : Xf;
            k_gemm128<<<g_gemm, threads, 0, stream>>>(Ain, Wl[l], nullptr, H, n, 0, 0);
            k_self_init<<<g_nd, threads, 0, stream>>>(H, dis, AGG, n);
            k_edge_agg<<<g_ed, threads, 0, stream>>>(src, dst, H, dis, AGG, e);
            k_finalize_relu<<<g_nd, threads, 0, stream>>>(AGG, bl[l], Xf, n);
        }
        // fc head: relu(X@Wf1+bf1) @ Wf2 + bf2
        k_gemm128<<<g_gemm, threads, 0, stream>>>(Xf, Wf1, bf1, H, n, 1, 1);
        k_gemm128<<<g_gemm, threads, 0, stream>>>(H, Wf2, bf2, outg, n, 1, 0);
    }
}

// Round 3
// 1464.599 us; speedup vs baseline: 2.1918x; 2.1918x over previous
//
#include <hip/hip_runtime.h>
#include <hip/hip_bf16.h>

#define D 128

// ---------------- small utility kernels ----------------

__global__ void k_zero_i32(int* __restrict__ p, int n) {
    int i = blockIdx.x * blockDim.x + threadIdx.x;
    if (i < n) p[i] = 0;
}

__global__ void k_count_deg(const int* __restrict__ dst, int* __restrict__ deg, int e) {
    int i = blockIdx.x * blockDim.x + threadIdx.x;
    if (i < e) atomicAdd(&deg[dst[i]], 1);
}

__global__ void k_dis(const int* __restrict__ deg, float* __restrict__ dis, int n) {
    int i = blockIdx.x * blockDim.x + threadIdx.x;
    if (i < n) dis[i] = rsqrtf((float)deg[i] + 1.0f);
}

// ---------------- prefix-sum (3-kernel block scan) → rowptr ----------------

__global__ __launch_bounds__(256) void k_scan1(const int* __restrict__ deg,
                                               int* __restrict__ rowptr,
                                               int* __restrict__ bsum, int n) {
    __shared__ int tmp[256];
    int t = threadIdx.x;
    int i = blockIdx.x * 256 + t;
    tmp[t] = (i < n) ? deg[i] : 0;
    __syncthreads();
    for (int ofs = 1; ofs < 256; ofs <<= 1) {
        int add = (t >= ofs) ? tmp[t - ofs] : 0;
        __syncthreads();
        tmp[t] += add;
        __syncthreads();
    }
    if (i < n) rowptr[i + 1] = tmp[t];               // inclusive within block
    if (t == 255) bsum[blockIdx.x] = tmp[255];
}

__global__ __launch_bounds__(256) void k_scan2(int* __restrict__ bsum, int nb) {
    __shared__ int tmp[256];
    int t = threadIdx.x;
    tmp[t] = (t < nb) ? bsum[t] : 0;
    __syncthreads();
    for (int ofs = 1; ofs < 256; ofs <<= 1) {
        int add = (t >= ofs) ? tmp[t - ofs] : 0;
        __syncthreads();
        tmp[t] += add;
        __syncthreads();
    }
    if (t < nb) bsum[t] = tmp[t];                    // inclusive
}

__global__ void k_scan3(int* __restrict__ rowptr, const int* __restrict__ bsum, int n) {
    int i = blockIdx.x * blockDim.x + threadIdx.x;
    if (i == 0) rowptr[0] = 0;
    if (i < n) {
        int b = i >> 8;
        if (b > 0) rowptr[i + 1] += bsum[b - 1];
    }
}

// scatter edges into CSR buckets (within-bucket order arbitrary — sum order only)
__global__ void k_csr_fill(const int* __restrict__ src, const int* __restrict__ dst,
                           const int* __restrict__ rowptr, int* __restrict__ cursor,
                           int* __restrict__ csr_src, int e) {
    int i = blockIdx.x * blockDim.x + threadIdx.x;
    if (i < e) {
        int d = dst[i];
        int pos = atomicAdd(&cursor[d], 1);
        csr_src[rowptr[d] + pos] = src[i];
    }
}

// ---------------- GEMM: C[n,128] = A[n,128] @ W[128,128] (+bias)(+relu) ----------------
// 32 rows x 128 cols per block; 256 threads; 16 outputs/thread (4 rows x 4 cols)

__global__ __launch_bounds__(256) void k_gemm128(
    const float* __restrict__ A, const float* __restrict__ W,
    const float* __restrict__ bias, float* __restrict__ C, int n,
    int fuse_bias, int fuse_relu) {
    __shared__ float Ws[D * D];        // 64 KiB
    __shared__ float AsT[D * 36];      // A transposed: AsT[k*36 + r], pad 36 (16B-aligned r0)
    int t = threadIdx.x;
    int row0 = blockIdx.x * 32;

    for (int i = t * 4; i < D * D; i += 1024)
        *(float4*)&Ws[i] = *(const float4*)&W[i];

    for (int i = t * 4; i < 32 * D; i += 1024) {
        int r = i >> 7, c = i & 127;                 // c multiple of 4
        int gr = row0 + r;
        float4 a = (gr < n) ? *(const float4*)&A[(size_t)gr * D + c]
                            : make_float4(0.f, 0.f, 0.f, 0.f);
        AsT[(c + 0) * 36 + r] = a.x;
        AsT[(c + 1) * 36 + r] = a.y;
        AsT[(c + 2) * 36 + r] = a.z;
        AsT[(c + 3) * 36 + r] = a.w;
    }
    __syncthreads();

    int c0 = (t & 31) * 4;
    int r0 = (t >> 5) * 4;
    float acc[4][4] = {};
    #pragma unroll 4
    for (int k = 0; k < D; ++k) {
        float4 a = *(const float4*)&AsT[k * 36 + r0];   // wave-broadcast
        float4 w = *(const float4*)&Ws[k * D + c0];
        acc[0][0] = fmaf(a.x, w.x, acc[0][0]);
        acc[0][1] = fmaf(a.x, w.y, acc[0][1]);
        acc[0][2] = fmaf(a.x, w.z, acc[0][2]);
        acc[0][3] = fmaf(a.x, w.w, acc[0][3]);
        acc[1][0] = fmaf(a.y, w.x, acc[1][0]);
        acc[1][1] = fmaf(a.y, w.y, acc[1][1]);
        acc[1][2] = fmaf(a.y, w.z, acc[1][2]);
        acc[1][3] = fmaf(a.y, w.w, acc[1][3]);
        acc[2][0] = fmaf(a.z, w.x, acc[2][0]);
        acc[2][1] = fmaf(a.z, w.y, acc[2][1]);
        acc[2][2] = fmaf(a.z, w.z, acc[2][2]);
        acc[2][3] = fmaf(a.z, w.w, acc[2][3]);
        acc[3][0] = fmaf(a.w, w.x, acc[3][0]);
        acc[3][1] = fmaf(a.w, w.y, acc[3][1]);
        acc[3][2] = fmaf(a.w, w.z, acc[3][2]);
        acc[3][3] = fmaf(a.w, w.w, acc[3][3]);
    }

    float4 bv = fuse_bias ? *(const float4*)&bias[c0] : make_float4(0.f, 0.f, 0.f, 0.f);
    #pragma unroll
    for (int j = 0; j < 4; ++j) {
        int r = row0 + r0 + j;
        if (r < n) {
            float4 o;
            o.x = acc[j][0] + bv.x;
            o.y = acc[j][1] + bv.y;
            o.z = acc[j][2] + bv.z;
            o.w = acc[j][3] + bv.w;
            if (fuse_relu) {
                o.x = fmaxf(o.x, 0.f); o.y = fmaxf(o.y, 0.f);
                o.z = fmaxf(o.z, 0.f); o.w = fmaxf(o.w, 0.f);
            }
            *(float4*)&C[(size_t)r * D + c0] = o;
        }
    }
}

// ---------------- fused GCN aggregation (gather, no atomics) ----------------
// one wave per dst node; 2 channels per lane
// X[v] = relu( sum_{s in N(v)} dis[s]*dis[v]*H[s] + dis[v]^2*H[v] + b )

__global__ __launch_bounds__(256) void k_csr_agg(
    const float* __restrict__ H, const int* __restrict__ rowptr,
    const int* __restrict__ csr_src, const float* __restrict__ dis,
    const float* __restrict__ bias, float* __restrict__ X, int n, int relu) {
    int wave = (blockIdx.x * 256 + threadIdx.x) >> 6;
    int lane = threadIdx.x & 63;
    if (wave >= n) return;
    int v = wave;
    float dv = dis[v];
    const float* Hv = H + (size_t)v * D;
    float acc0 = Hv[lane] * dv * dv;
    float acc1 = Hv[lane + 64] * dv * dv;
    int beg = rowptr[v], end = rowptr[v + 1];
    for (int j = beg; j < end; ++j) {
        int s = csr_src[j];
        float w = dis[s] * dv;
        const float* Hs = H + (size_t)s * D;
        acc0 = fmaf(Hs[lane], w, acc0);
        acc1 = fmaf(Hs[lane + 64], w, acc1);
    }
    acc0 += bias[lane];
    acc1 += bias[lane + 64];
    if (relu) { acc0 = fmaxf(acc0, 0.f); acc1 = fmaxf(acc1, 0.f); }
    X[(size_t)v * D + lane] = acc0;
    X[(size_t)v * D + lane + 64] = acc1;
}

// ---------------- launcher ----------------

extern "C" void kernel_launch(void* const* d_in, const int* in_sizes, int n_in,
                              void* d_out, int out_size, void* d_ws, size_t ws_size,
                              hipStream_t stream) {
    const float* x    = (const float*)d_in[0];
    const int*   ei   = (const int*)d_in[1];
    const float* xa   = (const float*)d_in[2];
    const int*   eia  = (const int*)d_in[3];
    const float* W_in = (const float*)d_in[4];
    const float* b_in = (const float*)d_in[5];
    const float* W_h  = (const float*)d_in[6];
    const float* b_h  = (const float*)d_in[7];
    const float* W_out= (const float*)d_in[8];
    const float* b_out= (const float*)d_in[9];
    const float* Wf1  = (const float*)d_in[10];
    const float* bf1  = (const float*)d_in[11];
    const float* Wf2  = (const float*)d_in[12];
    const float* bf2  = (const float*)d_in[13];

    const int n = in_sizes[0] / D;       // 50000
    const int e = in_sizes[1] / 2;       // 800000

    float* Xf     = (float*)d_ws;                  // activations [n,128]
    float* H      = Xf + (size_t)n * D;            // X@W         [n,128]
    float* dis    = H  + (size_t)n * D;            // [n]
    int*   deg    = (int*)(dis + n);               // [n]
    int*   rowptr = deg + n;                       // [n+1]
    int*   cursor = rowptr + (n + 1);              // [n]
    int*   bsum   = cursor + n;                    // [256]
    int*   csrsrc = bsum + 256;                    // [e]

    float* out = (float*)d_out;

    const float* Wl[3] = {W_in, W_h, W_out};
    const float* bl[3] = {b_in, b_h, b_out};

    const int threads = 256;
    const int g_n    = (n + threads - 1) / threads;        // 196
    const int g_e    = (e + threads - 1) / threads;
    const int g_gemm = (n + 31) / 32;                      // 1563
    const int g_agg  = (n * 64 + threads - 1) / threads;   // 12500

    for (int g = 0; g < 2; ++g) {
        const float* xin = g ? xa : x;
        const int* src  = g ? eia : ei;        // edge_index[0]
        const int* dst  = src + e;             // edge_index[1]
        float* outg = out + (size_t)g * n * D;

        // ---- build CSR for this graph ----
        k_zero_i32<<<g_n, threads, 0, stream>>>(deg, n);
        k_zero_i32<<<g_n, threads, 0, stream>>>(cursor, n);
        k_count_deg<<<g_e, threads, 0, stream>>>(dst, deg, e);
        k_dis<<<g_n, threads, 0, stream>>>(deg, dis, n);
        k_scan1<<<g_n, threads, 0, stream>>>(deg, rowptr, bsum, n);
        k_scan2<<<1, threads, 0, stream>>>(bsum, g_n);
        k_scan3<<<g_n, threads, 0, stream>>>(rowptr, bsum, n);
        k_csr_fill<<<g_e, threads, 0, stream>>>(src, dst, rowptr, cursor, csrsrc, e);

        // ---- 3 GCN layers ----
        for (int l = 0; l < 3; ++l) {
            const float* Ain = (l == 0) ? xin : Xf;
            k_gemm128<<<g_gemm, threads, 0, stream>>>(Ain, Wl[l], nullptr, H, n, 0, 0);
            k_csr_agg<<<g_agg, threads, 0, stream>>>(H, rowptr, csrsrc, dis, bl[l], Xf, n, 1);
        }

        // ---- fc head: relu(X@Wf1+bf1) @ Wf2 + bf2 ----
        k_gemm128<<<g_gemm, threads, 0, stream>>>(Xf, Wf1, bf1, H, n, 1, 1);
        k_gemm128<<<g_gemm, threads, 0, stream>>>(H, Wf2, bf2, outg, n, 1, 0);
    }
}

// Round 9
// 921.692 us; speedup vs baseline: 3.4828x; 1.5890x over previous
//
#include <hip/hip_runtime.h>
#include <hip/hip_bf16.h>

#define D 128

typedef __bf16 bf16x8 __attribute__((ext_vector_type(8)));
typedef float  f32x4  __attribute__((ext_vector_type(4)));

// ---------------- small utility kernels ----------------

__global__ void k_zero_i32(int* __restrict__ p, int n) {
    int i = blockIdx.x * blockDim.x + threadIdx.x;
    if (i < n) p[i] = 0;
}

__global__ void k_copy_i32(int* __restrict__ dst, const int* __restrict__ src, int n) {
    int i = blockIdx.x * blockDim.x + threadIdx.x;
    if (i < n) dst[i] = src[i];
}

__global__ void k_count_deg(const int* __restrict__ dst, int* __restrict__ deg, int e) {
    int i = blockIdx.x * blockDim.x + threadIdx.x;
    if (i < e) atomicAdd(&deg[dst[i]], 1);
}

__global__ void k_dis(const int* __restrict__ deg, float* __restrict__ dis, int n) {
    int i = blockIdx.x * blockDim.x + threadIdx.x;
    if (i < n) dis[i] = rsqrtf((float)deg[i] + 1.0f);
}

// ---------------- prefix-sum (3-kernel block scan) → rowptr ----------------

__global__ __launch_bounds__(256) void k_scan1(const int* __restrict__ deg,
                                               int* __restrict__ rowptr,
                                               int* __restrict__ bsum, int n) {
    __shared__ int tmp[256];
    int t = threadIdx.x;
    int i = blockIdx.x * 256 + t;
    tmp[t] = (i < n) ? deg[i] : 0;
    __syncthreads();
    for (int ofs = 1; ofs < 256; ofs <<= 1) {
        int add = (t >= ofs) ? tmp[t - ofs] : 0;
        __syncthreads();
        tmp[t] += add;
        __syncthreads();
    }
    if (i < n) rowptr[i + 1] = tmp[t];
    if (t == 255) bsum[blockIdx.x] = tmp[255];
}

__global__ __launch_bounds__(256) void k_scan2(int* __restrict__ bsum, int nb) {
    __shared__ int tmp[256];
    int t = threadIdx.x;
    tmp[t] = (t < nb) ? bsum[t] : 0;
    __syncthreads();
    for (int ofs = 1; ofs < 256; ofs <<= 1) {
        int add = (t >= ofs) ? tmp[t - ofs] : 0;
        __syncthreads();
        tmp[t] += add;
        __syncthreads();
    }
    if (t < nb) bsum[t] = tmp[t];
}

__global__ void k_scan3(int* __restrict__ rowptr, const int* __restrict__ bsum, int n) {
    int i = blockIdx.x * blockDim.x + threadIdx.x;
    if (i == 0) rowptr[0] = 0;
    if (i < n) {
        int b = i >> 8;
        if (b > 0) rowptr[i + 1] += bsum[b - 1];
    }
}

// cursor pre-initialized to rowptr: atomic gives absolute position directly
__global__ void k_csr_fill(const int* __restrict__ src, const int* __restrict__ dst,
                           int* __restrict__ cursor, int* __restrict__ csr_src, int e) {
    int i = blockIdx.x * blockDim.x + threadIdx.x;
    if (i < e) {
        int pos = atomicAdd(&cursor[dst[i]], 1);
        csr_src[pos] = src[i];
    }
}

// ---------------- weight packing: f32 W[128][128] -> per-lane MFMA frag order ----------------
// slot i = ((kb*8 + ct)*64 + lane)*8 + j  ->  W[kb*32 + (lane>>4)*8 + j][ct*16 + (lane&15)]
// hi at out[q*32768 + i], lo at out[q*32768 + 16384 + i]

__global__ __launch_bounds__(256) void k_pack_w5(
    const float* __restrict__ w0, const float* __restrict__ w1,
    const float* __restrict__ w2, const float* __restrict__ w3,
    const float* __restrict__ w4, __bf16* __restrict__ out) {
    int q = blockIdx.x >> 6;
    const float* W = (q == 0) ? w0 : (q == 1) ? w1 : (q == 2) ? w2 : (q == 3) ? w3 : w4;
    int i = ((blockIdx.x & 63) << 8) | threadIdx.x;      // 0..16383
    int j    = i & 7;
    int lane = (i >> 3) & 63;
    int ct   = (i >> 9) & 7;
    int kb   = i >> 12;
    int k = kb * 32 + (lane >> 4) * 8 + j;
    int c = ct * 16 + (lane & 15);
    float w = W[k * D + c];
    __bf16 hi = (__bf16)w;
    __bf16 lo = (__bf16)(w - (float)hi);
    __bf16* dstp = out + (size_t)q * 32768;
    dstp[i] = hi;
    dstp[16384 + i] = lo;
}

// ---------------- split-bf16 MFMA GEMM: C[n,128] = A[n,128] @ W + (bias)(relu) ----------------
// 256 thr = 4 waves; wave computes 16 rows x 128 cols; 64 rows/block.

__global__ __launch_bounds__(256) void k_gemm_mfma(
    const float* __restrict__ A, const __bf16* __restrict__ Wp,
    const float* __restrict__ bias, float* __restrict__ C, int n,
    int fuse_bias, int fuse_relu) {
    __shared__ __bf16 Ws[32768];     // 64 KiB: [0..16383]=hi, [16384..]=lo (frag-packed)
    int t = threadIdx.x;
    for (int i = t * 8; i < 32768; i += 2048)
        *(float4*)&Ws[i] = *(const float4*)&Wp[i];

    int wv = t >> 6, lane = t & 63;
    int lrow = lane & 15, lhi = lane >> 4;
    int m0 = blockIdx.x * 64 + wv * 16;

    // A fragments (split to hi/lo bf16) — direct from global, one row per lane&15
    bf16x8 ahi[4], alo[4];
    int arow = m0 + lrow;
    const float* ap = A + (size_t)arow * D + lhi * 8;
    #pragma unroll
    for (int kb = 0; kb < 4; ++kb) {
        float av[8];
        if (arow < n) {
            float4 p0 = *(const float4*)(ap + kb * 32);
            float4 p1 = *(const float4*)(ap + kb * 32 + 4);
            av[0] = p0.x; av[1] = p0.y; av[2] = p0.z; av[3] = p0.w;
            av[4] = p1.x; av[5] = p1.y; av[6] = p1.z; av[7] = p1.w;
        } else {
            #pragma unroll
            for (int j = 0; j < 8; ++j) av[j] = 0.0f;
        }
        #pragma unroll
        for (int j = 0; j < 8; ++j) {
            __bf16 h = (__bf16)av[j];
            ahi[kb][j] = h;
            alo[kb][j] = (__bf16)(av[j] - (float)h);
        }
    }
    __syncthreads();

    f32x4 acc[8];
    f32x4 zz = {0.f, 0.f, 0.f, 0.f};
    #pragma unroll
    for (int i = 0; i < 8; ++i) acc[i] = zz;

    #pragma unroll
    for (int kb = 0; kb < 4; ++kb) {
        #pragma unroll
        for (int ct = 0; ct < 8; ++ct) {
            int off = ((kb * 8 + ct) * 64 + lane) * 8;
            bf16x8 bh = *(const bf16x8*)&Ws[off];
            bf16x8 bl = *(const bf16x8*)&Ws[16384 + off];
            acc[ct] = __builtin_amdgcn_mfma_f32_16x16x32_bf16(ahi[kb], bh, acc[ct], 0, 0, 0);
            acc[ct] = __builtin_amdgcn_mfma_f32_16x16x32_bf16(ahi[kb], bl, acc[ct], 0, 0, 0);
            acc[ct] = __builtin_amdgcn_mfma_f32_16x16x32_bf16(alo[kb], bh, acc[ct], 0, 0, 0);
        }
    }

    // epilogue: C/D layout col=lane&15, row=(lane>>4)*4+reg  [verified m89/m91]
    #pragma unroll
    for (int ct = 0; ct < 8; ++ct) {
        int col = ct * 16 + lrow;
        float bv = fuse_bias ? bias[col] : 0.0f;
        #pragma unroll
        for (int r = 0; r < 4; ++r) {
            int row = m0 + lhi * 4 + r;
            if (row < n) {
                float v = acc[ct][r] + bv;
                if (fuse_relu) v = fmaxf(v, 0.0f);
                C[(size_t)row * D + col] = v;
            }
        }
    }
}

// ---------------- fused GCN aggregation (gather, no atomics) ----------------
// one wave per dst node; 2 channels/lane; scalarized indices + 4x unroll

__global__ __launch_bounds__(256) void k_csr_agg(
    const float* __restrict__ H, const int* __restrict__ rowptr,
    const int* __restrict__ csr_src, const float* __restrict__ dis,
    const float* __restrict__ bias, float* __restrict__ X, int n, int relu) {
    int wid = (blockIdx.x * 256 + threadIdx.x) >> 6;
    int lane = threadIdx.x & 63;
    int v = __builtin_amdgcn_readfirstlane(wid);   // wave-uniform -> SGPR
    if (v >= n) return;
    float dv = dis[v];
    const float* Hv = H + (size_t)v * D;
    float acc0 = Hv[lane] * dv * dv;
    float acc1 = Hv[lane + 64] * dv * dv;
    int beg = rowptr[v], end = rowptr[v + 1];
    int j = beg;
    for (; j + 4 <= end; j += 4) {
        int s0 = csr_src[j + 0], s1 = csr_src[j + 1];
        int s2 = csr_src[j + 2], s3 = csr_src[j + 3];
        float w0 = dis[s0] * dv, w1 = dis[s1] * dv;
        float w2 = dis[s2] * dv, w3 = dis[s3] * dv;
        const float* p0 = H + (size_t)s0 * D;
        const float* p1 = H + (size_t)s1 * D;
        const float* p2 = H + (size_t)s2 * D;
        const float* p3 = H + (size_t)s3 * D;
        float a0 = p0[lane], b0 = p0[lane + 64];
        float a1 = p1[lane], b1 = p1[lane + 64];
        float a2 = p2[lane], b2 = p2[lane + 64];
        float a3 = p3[lane], b3 = p3[lane + 64];
        acc0 = fmaf(a0, w0, acc0); acc1 = fmaf(b0, w0, acc1);
        acc0 = fmaf(a1, w1, acc0); acc1 = fmaf(b1, w1, acc1);
        acc0 = fmaf(a2, w2, acc0); acc1 = fmaf(b2, w2, acc1);
        acc0 = fmaf(a3, w3, acc0); acc1 = fmaf(b3, w3, acc1);
    }
    for (; j < end; ++j) {
        int s = csr_src[j];
        float w = dis[s] * dv;
        const float* p = H + (size_t)s * D;
        acc0 = fmaf(p[lane], w, acc0);
        acc1 = fmaf(p[lane + 64], w, acc1);
    }
    acc0 += bias[lane];
    acc1 += bias[lane + 64];
    if (relu) { acc0 = fmaxf(acc0, 0.f); acc1 = fmaxf(acc1, 0.f); }
    X[(size_t)v * D + lane] = acc0;
    X[(size_t)v * D + lane + 64] = acc1;
}

// ---------------- launcher ----------------

extern "C" void kernel_launch(void* const* d_in, const int* in_sizes, int n_in,
                              void* d_out, int out_size, void* d_ws, size_t ws_size,
                              hipStream_t stream) {
    const float* x    = (const float*)d_in[0];
    const int*   ei   = (const int*)d_in[1];
    const float* xa   = (const float*)d_in[2];
    const int*   eia  = (const int*)d_in[3];
    const float* W_in = (const float*)d_in[4];
    const float* b_in = (const float*)d_in[5];
    const float* W_h  = (const float*)d_in[6];
    const float* b_h  = (const float*)d_in[7];
    const float* W_out= (const float*)d_in[8];
    const float* b_out= (const float*)d_in[9];
    const float* Wf1  = (const float*)d_in[10];
    const float* bf1  = (const float*)d_in[11];
    const float* Wf2  = (const float*)d_in[12];
    const float* bf2  = (const float*)d_in[13];

    const int n = in_sizes[0] / D;       // 50000
    const int e = in_sizes[1] / 2;       // 800000

    float* Xf     = (float*)d_ws;                  // [n,128]
    float* H      = Xf + (size_t)n * D;            // [n,128]
    float* dis    = H  + (size_t)n * D;            // [n]
    int*   deg    = (int*)(dis + n);               // [n]
    int*   rowptr = deg + n;                       // [n+4] (padded for 16B alignment)
    int*   cursor = rowptr + (n + 4);              // [n]
    int*   bsum   = cursor + n;                    // [256]
    int*   csrsrc = bsum + 256;                    // [e]
    __bf16* wpack = (__bf16*)(csrsrc + e);         // 5 * 32768 bf16 = 320 KB

    float* out = (float*)d_out;

    const float* bl[3] = {b_in, b_h, b_out};

    const int threads = 256;
    const int g_n    = (n + threads - 1) / threads;
    const int g_e    = (e + threads - 1) / threads;
    const int g_gemm = (n + 63) / 64;                      // 782
    const int g_agg  = (n * 64 + threads - 1) / threads;   // 12500

    // pack all 5 weight matrices (hi/lo split, frag order) once
    k_pack_w5<<<320, threads, 0, stream>>>(W_in, W_h, W_out, Wf1, Wf2, wpack);

    for (int g = 0; g < 2; ++g) {
        const float* xin = g ? xa : x;
        const int* src  = g ? eia : ei;        // edge_index[0]
        const int* dst  = src + e;             // edge_index[1]
        float* outg = out + (size_t)g * n * D;

        // ---- build CSR ----
        k_zero_i32<<<g_n, threads, 0, stream>>>(deg, n);
        k_count_deg<<<g_e, threads, 0, stream>>>(dst, deg, e);
        k_dis<<<g_n, threads, 0, stream>>>(deg, dis, n);
        k_scan1<<<g_n, threads, 0, stream>>>(deg, rowptr, bsum, n);
        k_scan2<<<1, threads, 0, stream>>>(bsum, g_n);
        k_scan3<<<g_n, threads, 0, stream>>>(rowptr, bsum, n);
        k_copy_i32<<<g_n, threads, 0, stream>>>(cursor, rowptr, n);
        k_csr_fill<<<g_e, threads, 0, stream>>>(src, dst, cursor, csrsrc, e);

        // ---- 3 GCN layers ----
        for (int l = 0; l < 3; ++l) {
            const float* Ain = (l == 0) ? xin : Xf;
            k_gemm_mfma<<<g_gemm, threads, 0, stream>>>(Ain, wpack + (size_t)l * 32768,
                                                        nullptr, H, n, 0, 0);
            k_csr_agg<<<g_agg, threads, 0, stream>>>(H, rowptr, csrsrc, dis, bl[l], Xf, n, 1);
        }

        // ---- fc head ----
        k_gemm_mfma<<<g_gemm, threads, 0, stream>>>(Xf, wpack + (size_t)3 * 32768,
                                                    bf1, H, n, 1, 1);
        k_gemm_mfma<<<g_gemm, threads, 0, stream>>>(H, wpack + (size_t)4 * 32768,
                                                    bf2, outg, n, 1, 0);
    }
}